// Round 11
// baseline (185.727 us; speedup 1.0000x reference)
//
#include <hip/hip_runtime.h>
#include <hip/hip_bf16.h>
#include <stdint.h>

typedef __attribute__((ext_vector_type(8))) short short8;
typedef __attribute__((ext_vector_type(4))) float float4v;
typedef __attribute__((ext_vector_type(4))) unsigned short ushort4v;

#define Bq 2
#define Sq 2048
#define Dq 1024
#define Hq 16
#define HDq 64

// 0.125 * log2(e): folded into Q at the QKV-GEMM epilogue so attention can use
// exp2 directly with no per-score scaling.
#define QSCALE 0.18033688011112042f

__device__ __forceinline__ unsigned short f2bf(float f) {
  union { float f; uint32_t u; } v; v.f = f;
  uint32_t r = (v.u + 0x7FFFu + ((v.u >> 16) & 1u)) >> 16;
  return (unsigned short)r;
}

// packed f32x2 -> bf16x2 (v_cvt_pk_bf16_f32 on gfx950)
__device__ __forceinline__ uint32_t pk2bf(float a, float b) {
  union { __hip_bfloat162 h; uint32_t u; } cv;
  cv.h = __float22bfloat162_rn(make_float2(a, b));
  return cv.u;
}

// async global->LDS, 16B per lane; LDS dest is wave-uniform base + lane*16.
__device__ __forceinline__ void gl_lds16(const unsigned short* g, unsigned short* l) {
  __builtin_amdgcn_global_load_lds(
      (const __attribute__((address_space(1))) void*)g,
      (__attribute__((address_space(3))) void*)l, 16, 0, 0);
}

// One launch: x (blocks 0..4095) + 4 weights (blocks 4096..8191, contiguous dst).
__global__ __launch_bounds__(256) void cvt_all_kernel(
    const float* __restrict__ x,
    const float* __restrict__ w0, const float* __restrict__ w1,
    const float* __restrict__ w2, const float* __restrict__ w3,
    unsigned short* __restrict__ xb, unsigned short* __restrict__ wb) {
  const int bid = blockIdx.x;
  const float* src;
  unsigned short* dst;
  int idx;
  if (bid < 4096) {
    src = x; dst = xb;
    idx = bid * 256 + threadIdx.x;
  } else {
    int j = (bid - 4096) * 256 + threadIdx.x;  // float4 index across 4 weights
    int z = j >> 18;                           // 262144 float4 per weight
    src = (z == 0) ? w0 : (z == 1) ? w1 : (z == 2) ? w2 : w3;
    dst = wb + (size_t)z * 1048576;            // 1M shorts per weight
    idx = j & 262143;
  }
  float4v f = ((const float4v*)src)[idx];
  ushort4v o;
#pragma unroll
  for (int q = 0; q < 4; q++) o[q] = f2bf(f[q]);
  ((ushort4v*)dst)[idx] = o;
}

// C = A(bf16 MxK) @ W^T. MT x 128 tile, BK=64, global_load_lds staging.
// LDS layout XOR-swizzled on 16B granules (phys_g = g ^ (row&7)).
// QKV epilogue: z==0 (Q) scales by QSCALE; z==2 (V) stores TRANSPOSED +
// sigma-permuted layout [bh][hd][sig(s)] so attention can stage V via
// global_load_lds with zero pack work. Each lane holds 4 consecutive tokens
// (quad*4+r) at fixed feature o; sigma keeps 4-aligned groups contiguous, so
// the store is one packed b64 at column sig(s0).
template <bool OUTPROJ, int MT>
__global__ __launch_bounds__(256) void gemm_bt_kernel(
    const unsigned short* __restrict__ A,
    const unsigned short* __restrict__ W0,
    const unsigned short* __restrict__ W1,
    const unsigned short* __restrict__ W2,
    unsigned short* __restrict__ q_dst,
    unsigned short* __restrict__ k_dst,
    unsigned short* __restrict__ v_dst,
    float* __restrict__ f_dst,
    const float* __restrict__ bias) {
  constexpr int K = 1024;
  constexpr int NMB = MT / 32;    // 16-row m-blocks per wave
  constexpr int APASS = MT / 32;  // staging passes for A (32 rows each)
  const int z = blockIdx.z;
  const unsigned short* W = (z == 0) ? W0 : (z == 1) ? W1 : W2;
  unsigned short* qkv = (z == 0) ? q_dst : (z == 1) ? k_dst : v_dst;

  __shared__ unsigned short Asm[MT * 64];
  __shared__ unsigned short Bsm[128 * 64];

  const int t = threadIdx.x;
  const int wave = t >> 6, lane = t & 63;
  const int quad = lane >> 4, l16 = lane & 15;
  const int wy = wave >> 1, wx = wave & 1;
  const int row0 = blockIdx.x * MT;
  const int col0 = blockIdx.y * 128;

  float4v zero = {0.f, 0.f, 0.f, 0.f};
  float4v acc[NMB][4];
#pragma unroll
  for (int i = 0; i < NMB; i++)
#pragma unroll
    for (int j = 0; j < 4; j++) acc[i][j] = zero;

  // staging geometry: pass i covers rows i*32..i*32+31; thread t -> row i*32+(t>>3),
  // phys granule t&7, logical granule (t&7)^((t>>3)&7). LDS slot = i*2048 + t*8.
  const int srow = t >> 3;
  const int sgl = ((t & 7) ^ (srow & 7)) << 3;  // logical col in shorts
  const unsigned short* gA[APASS];
  const unsigned short* gB[4];
#pragma unroll
  for (int i = 0; i < APASS; i++)
    gA[i] = A + (size_t)(row0 + i * 32 + srow) * K + sgl;
#pragma unroll
  for (int i = 0; i < 4; i++)
    gB[i] = W + (size_t)(col0 + i * 32 + srow) * K + sgl;

  const int swl = (l16 & 7);  // frag-read swizzle key

  for (int k0 = 0; k0 < K; k0 += 64) {
#pragma unroll
    for (int i = 0; i < APASS; i++) gl_lds16(gA[i] + k0, &Asm[i * 2048 + t * 8]);
#pragma unroll
    for (int i = 0; i < 4; i++) gl_lds16(gB[i] + k0, &Bsm[i * 2048 + t * 8]);
    __syncthreads();
    short8 af[NMB][2], bf[4][2];
#pragma unroll
    for (int ks = 0; ks < 2; ks++) {
#pragma unroll
      for (int mb = 0; mb < NMB; mb++) {
        int row = wy * (MT / 2) + mb * 16 + l16;
        int pg = (ks * 4 + quad) ^ swl;
        af[mb][ks] = *(const short8*)(&Asm[row * 64 + pg * 8]);
      }
#pragma unroll
      for (int nb = 0; nb < 4; nb++) {
        int row = wx * 64 + nb * 16 + l16;
        int pg = (ks * 4 + quad) ^ swl;
        bf[nb][ks] = *(const short8*)(&Bsm[row * 64 + pg * 8]);
      }
    }
#pragma unroll
    for (int ks = 0; ks < 2; ks++)
#pragma unroll
      for (int mb = 0; mb < NMB; mb++)
#pragma unroll
        for (int nb = 0; nb < 4; nb++)
          acc[mb][nb] = __builtin_amdgcn_mfma_f32_16x16x32_bf16(af[mb][ks], bf[nb][ks], acc[mb][nb], 0, 0, 0);
    __syncthreads();
  }

  const float qsc = (!OUTPROJ && z == 0) ? QSCALE : 1.0f;
#pragma unroll
  for (int mb = 0; mb < NMB; mb++) {
#pragma unroll
    for (int nb = 0; nb < 4; nb++) {
      if (OUTPROJ) {
#pragma unroll
        for (int r = 0; r < 4; r++) {
          int row = row0 + wy * (MT / 2) + mb * 16 + quad * 4 + r;
          int o = col0 + wx * 64 + nb * 16 + l16;
          f_dst[(size_t)row * 1024 + o] = acc[mb][nb][r] + bias[o];
        }
      } else if (z == 2) {
        // V^T + sigma: rowb = 4-aligned token base (b constant across r).
        int rowb = row0 + wy * (MT / 2) + mb * 16 + quad * 4;
        int b = rowb >> 11, s0 = rowb & 2047;
        int o = col0 + wx * 64 + nb * 16 + l16;
        int h = o >> 6, hd = o & 63;
        int c = (s0 & ~31) + (((s0 >> 2) & 3) << 3) + (((s0 >> 4) & 1) << 2);
        ushort4v p4;
#pragma unroll
        for (int r = 0; r < 4; r++) p4[r] = f2bf(acc[mb][nb][r]);
        *(ushort4v*)(qkv + ((size_t)((b * Hq + h) * HDq + hd)) * Sq + c) = p4;
      } else {
#pragma unroll
        for (int r = 0; r < 4; r++) {
          int row = row0 + wy * (MT / 2) + mb * 16 + quad * 4 + r;
          int o = col0 + wx * 64 + nb * 16 + l16;
          int b = row >> 11, s = row & 2047;
          int h = o >> 6, hd = o & 63;
          qkv[(size_t)((b * Hq + h) * Sq + s) * HDq + hd] = f2bf(acc[mb][nb][r] * qsc);
        }
      }
    }
  }
}

// Flash attention v11: 64q-per-wave amortization at 3 blocks/CU.
// v9 ledger: LDS frag reads ~20.5us were the largest pole; reads per MFMA
// scale as 1/(q per wave). v11 doubles q/wave (32->64) halving kf+vf reads
// per unit work, while avoiding the v3 occupancy cliff by using 256-thread
// blocks: 4 waves = 2 q-groups(64q) x 2 key-groups(32keys), 64-key K/V
// tiles, 32KB staging LDS. Unified reg ~160 (AGPR 80 acc + ~80 VGPR) ->
// 3 blocks/CU = 3 waves/SIMD (capped via launch_bounds(256,3)).
// All geometries individually verified: K staging/frag-read = v8's exact
// 256-thread 64-key path; V^T gl_lds staging = v9's path at 8 granules/row
// (bank math: 128B row stride cancels mod 32 banks; phys=(wk*4+quad)^(l16&7)
// -> 2-way, free); epilogue = v9's wk-combine with (wq,qb) re-indexed.
// XCD-swizzled flat grid kept (FETCH 4x drop).
__global__ __launch_bounds__(256, 3) void attn_kernel(
    const unsigned short* __restrict__ Q,
    const unsigned short* __restrict__ Kg,
    const unsigned short* __restrict__ Vt,
    unsigned short* __restrict__ ctx) {
  constexpr int KBUF = 4096;  // shorts per K buffer (64 keys x 64 hd, swizzled)
  constexpr int VBUF = 4096;  // shorts per V^T buffer (64 hd x 64 keys, swizzled)
  constexpr int QSTR = 132;   // obuf q-dim stride (f32)
  __shared__ __align__(16) unsigned char smem[34816];
  unsigned short* Ksm = (unsigned short*)smem;            // [2][4096]
  unsigned short* Vsm = (unsigned short*)(smem + 16384);  // [2][4096]
  float* obuf = (float*)smem;                             // combine: [64 hd][132 q]
  float* dbuf = (float*)(smem + 33792);                   // combine: [128]

  const int wgid = blockIdx.x;
  const int lid = wgid >> 3;
  const int bh = (wgid & 7) * 4 + (lid >> 4);  // XCD-co-located bh
  const int q0 = (lid & 15) * 128;
  const int t = threadIdx.x;
  const int wave = t >> 6, lane = t & 63;
  const int quad = lane >> 4, l16 = lane & 15;
  const int wq = wave >> 1, wk = wave & 1;
  const int swl = l16 & 7;

  const unsigned short* Qb = Q + (size_t)bh * Sq * HDq;
  const unsigned short* Kb = Kg + (size_t)bh * Sq * HDq;
  const unsigned short* Vb = Vt + (size_t)bh * HDq * Sq;  // V^T base

  // Q fragments: wave's 64 q rows (B-operand of QK^T S^T-trick MFMA)
  short8 qf[4][2];
#pragma unroll
  for (int qb = 0; qb < 4; qb++)
#pragma unroll
    for (int ks = 0; ks < 2; ks++)
      qf[qb][ks] = *(const short8*)(Qb + (size_t)(q0 + wq * 64 + qb * 16 + l16) * HDq + ks * 32 + quad * 8);

  short8 ones;
#pragma unroll
  for (int j = 0; j < 8; j++) ones[j] = (short)0x3F80;  // bf16 1.0

  float4v zero = {0.f, 0.f, 0.f, 0.f};
  float4v of[4][4];   // [qb][hb]; D layout row=q (quad*4+r), col=hd (l16)
  float4v dsum[4];
#pragma unroll
  for (int qb = 0; qb < 4; qb++) {
    dsum[qb] = zero;
#pragma unroll
    for (int hb = 0; hb < 4; hb++) of[qb][hb] = zero;
  }

  // K staging (v8-verified): 2 passes x 256 threads x 16B cover 64 rows.
  // Pass i row = i*32 + (t>>3); XOR swizzle pre-applied to global address.
  const int srow = t >> 3;
  const unsigned short* gK = Kb + (size_t)srow * 64 + (((t & 7) ^ (srow & 7)) << 3);

  // V^T staging: 2 passes; pass i covers hd rows i*32 + (t>>3); 8 granules
  // per 128B row, logical granule (t&7)^(row&7) pre-applied (row&7 is
  // pass-invariant).
  const unsigned short* gV = Vb + (size_t)srow * Sq + (((t & 7) ^ (srow & 7)) << 3);

#define KISSUE(off, bufsel) do {                                     \
    gl_lds16(gK + (size_t)(off) * 64, &Ksm[(bufsel) * KBUF + t * 8]);\
    gl_lds16(gK + (size_t)(off) * 64 + 2048,                         \
             &Ksm[(bufsel) * KBUF + 2048 + t * 8]);                  \
  } while (0)

#define VISSUE(off, bufsel) do {                                     \
    gl_lds16(gV + (off), &Vsm[(bufsel) * VBUF + t * 8]);             \
    gl_lds16(gV + (off) + 32 * Sq,                                   \
             &Vsm[(bufsel) * VBUF + 2048 + t * 8]);                  \
  } while (0)

  // one 64-key tile = one 32-key substep per wave (wave owns key half wk).
  // kf shared across 4 qb; vf[hb] shared across 4 qb.
#define PSTEP(BUF) do {                                                        \
    const int kb0 = (BUF) * KBUF + wk * 2048;                                  \
    short8 kf[2][2];                                                           \
    _Pragma("unroll")                                                          \
    for (int s = 0; s < 2; s++)                                                \
      _Pragma("unroll")                                                        \
      for (int ks = 0; ks < 2; ks++)                                           \
        kf[s][ks] = *(const short8*)&Ksm[kb0 + (s * 16 + l16) * 64 + ((ks * 4 + quad) ^ swl) * 8]; \
    short8 pfr[4];                                                             \
    _Pragma("unroll")                                                          \
    for (int qb = 0; qb < 4; qb++) {                                           \
      float4v sa = zero, sb = zero;                                            \
      _Pragma("unroll")                                                        \
      for (int ks = 0; ks < 2; ks++) {                                         \
        sa = __builtin_amdgcn_mfma_f32_16x16x32_bf16(kf[0][ks], qf[qb][ks], sa, 0, 0, 0); \
        sb = __builtin_amdgcn_mfma_f32_16x16x32_bf16(kf[1][ks], qf[qb][ks], sb, 0, 0, 0); \
      }                                                                        \
      union { uint32_t u[4]; short8 v; } pw;                                   \
      pw.u[0] = pk2bf(__builtin_amdgcn_exp2f(sa[0]), __builtin_amdgcn_exp2f(sa[1])); \
      pw.u[1] = pk2bf(__builtin_amdgcn_exp2f(sa[2]), __builtin_amdgcn_exp2f(sa[3])); \
      pw.u[2] = pk2bf(__builtin_amdgcn_exp2f(sb[0]), __builtin_amdgcn_exp2f(sb[1])); \
      pw.u[3] = pk2bf(__builtin_amdgcn_exp2f(sb[2]), __builtin_amdgcn_exp2f(sb[3])); \
      pfr[qb] = pw.v;                                                          \
    }                                                                          \
    _Pragma("unroll")                                                          \
    for (int qb = 0; qb < 4; qb++)                                             \
      dsum[qb] = __builtin_amdgcn_mfma_f32_16x16x32_bf16(pfr[qb], ones, dsum[qb], 0, 0, 0); \
    _Pragma("unroll")                                                          \
    for (int hb = 0; hb < 4; hb++) {                                           \
      short8 vf = *(const short8*)&Vsm[(BUF) * VBUF + (hb * 16 + l16) * 64 + ((wk * 4 + quad) ^ swl) * 8]; \
      _Pragma("unroll")                                                        \
      for (int qb = 0; qb < 4; qb++)                                           \
        of[qb][hb] = __builtin_amdgcn_mfma_f32_16x16x32_bf16(pfr[qb], vf, of[qb][hb], 0, 0, 0); \
    }                                                                          \
  } while (0)

  // prologue: tile 0 into buf0; barrier drains; tile 1 into buf1 (in flight
  // during tile-0 compute, drained by the in-loop barrier).
  KISSUE(0, 0);
  VISSUE(0, 0);
  __syncthreads();
  KISSUE(64, 1);
  VISSUE(64, 1);

  for (int kt = 0; kt < Sq; kt += 64) {
    const int cur = (kt >> 6) & 1;
    PSTEP(cur);
    __syncthreads();
    if (kt + 128 < Sq) {
      KISSUE(kt + 128, cur);
      VISSUE(kt + 128, cur);
    }
  }

  // combine the 2 key-group partials in LDS: obuf[hd][q] f32, float4 stores
  // along q (quad*4+r contiguous). Overlays K/V buffers (safe after barrier).
  if (wk == 0) {
#pragma unroll
    for (int qb = 0; qb < 4; qb++) {
#pragma unroll
      for (int hb = 0; hb < 4; hb++)
        *(float4v*)&obuf[(hb * 16 + l16) * QSTR + wq * 64 + qb * 16 + quad * 4] = of[qb][hb];
      if (l16 == 0)
#pragma unroll
        for (int r = 0; r < 4; r++)
          dbuf[wq * 64 + qb * 16 + quad * 4 + r] = dsum[qb][r];
    }
  }
  __syncthreads();
  if (wk == 1) {
#pragma unroll
    for (int qb = 0; qb < 4; qb++) {
#pragma unroll
      for (int hb = 0; hb < 4; hb++) {
        float4v* pp = (float4v*)&obuf[(hb * 16 + l16) * QSTR + wq * 64 + qb * 16 + quad * 4];
        float4v o = *pp;
        o += of[qb][hb];
        *pp = o;
      }
      if (l16 == 0)
#pragma unroll
        for (int r = 0; r < 4; r++)
          dbuf[wq * 64 + qb * 16 + quad * 4 + r] += dsum[qb][r];
    }
  }
  __syncthreads();

  // final store: thread t -> q row (t&127), 32-hd half (t>>7)
  const int b = bh >> 4, h = bh & 15;
  const int qq = t & 127, hseg = t >> 7;
  const float dinv = 1.0f / dbuf[qq];
  unsigned short* cp = ctx + ((size_t)(b * Sq + q0 + qq)) * Dq + h * 64 + hseg * 32;
#pragma unroll
  for (int g = 0; g < 4; g++) {
    short8 o8;
#pragma unroll
    for (int j = 0; j < 8; j++)
      o8[j] = (short)f2bf(obuf[(hseg * 32 + g * 8 + j) * QSTR + qq] * dinv);
    *(short8*)(cp + g * 8) = o8;
  }
#undef KISSUE
#undef VISSUE
#undef PSTEP
}

extern "C" void kernel_launch(void* const* d_in, const int* in_sizes, int n_in,
                              void* d_out, int out_size, void* d_ws, size_t ws_size,
                              hipStream_t stream) {
  (void)in_sizes; (void)n_in; (void)out_size; (void)ws_size;
  const float* x  = (const float*)d_in[0];
  const float* wq = (const float*)d_in[1];
  const float* wk = (const float*)d_in[2];
  const float* wv = (const float*)d_in[3];
  const float* wo = (const float*)d_in[4];
  const float* bo = (const float*)d_in[5];
  float* out = (float*)d_out;

  char* ws = (char*)d_ws;
  const size_t MB = 1u << 20;
  unsigned short* xb  = (unsigned short*)(ws + 0 * MB);   // 8 MB  (4096x1024 bf16)
  unsigned short* wqb = (unsigned short*)(ws + 8 * MB);   // 2 MB each, contiguous
  unsigned short* wkb = (unsigned short*)(ws + 10 * MB);
  unsigned short* wvb = (unsigned short*)(ws + 12 * MB);
  unsigned short* wob = (unsigned short*)(ws + 14 * MB);
  unsigned short* qb  = (unsigned short*)(ws + 16 * MB);  // 8 MB  (B,H,S,HD), pre-scaled
  unsigned short* kb  = (unsigned short*)(ws + 24 * MB);  // 8 MB
  unsigned short* vb  = (unsigned short*)(ws + 32 * MB);  // 8 MB  (B,H,HD,sig(S)) V^T
  unsigned short* cxb = (unsigned short*)(ws + 40 * MB);  // 8 MB  (B,S,D)

  cvt_all_kernel<<<8192, 256, 0, stream>>>(x, wq, wk, wv, wo, xb, wqb);

  gemm_bt_kernel<false, 128><<<dim3(32, 8, 3), 256, 0, stream>>>(
      xb, wqb, wkb, wvb, qb, kb, vb, nullptr, nullptr);
  attn_kernel<<<dim3(512), 256, 0, stream>>>(qb, kb, vb, cxb);
  // outproj: MT=64 (512 blocks = 2 blocks/CU). MT=128's 256 blocks = 1
  // block/CU = 1 wave/SIMD regressed ~6us at this skinny N=1024 shape.
  gemm_bt_kernel<true, 64><<<dim3(64, 8, 1), 256, 0, stream>>>(
      cxb, wob, wob, wob, nullptr, nullptr, nullptr, out, bo);
}

// Round 12
// 178.977 us; speedup vs baseline: 1.0377x; 1.0377x over previous
//
#include <hip/hip_runtime.h>
#include <hip/hip_bf16.h>
#include <stdint.h>

typedef __attribute__((ext_vector_type(8))) short short8;
typedef __attribute__((ext_vector_type(4))) float float4v;
typedef __attribute__((ext_vector_type(4))) unsigned short ushort4v;

#define Bq 2
#define Sq 2048
#define Dq 1024
#define Hq 16
#define HDq 64

// 0.125 * log2(e): folded into Q at the QKV-GEMM epilogue so attention can use
// exp2 directly with no per-score scaling.
#define QSCALE 0.18033688011112042f

__device__ __forceinline__ unsigned short f2bf(float f) {
  union { float f; uint32_t u; } v; v.f = f;
  uint32_t r = (v.u + 0x7FFFu + ((v.u >> 16) & 1u)) >> 16;
  return (unsigned short)r;
}

// packed f32x2 -> bf16x2 (v_cvt_pk_bf16_f32 on gfx950)
__device__ __forceinline__ uint32_t pk2bf(float a, float b) {
  union { __hip_bfloat162 h; uint32_t u; } cv;
  cv.h = __float22bfloat162_rn(make_float2(a, b));
  return cv.u;
}

// async global->LDS, 16B per lane; LDS dest is wave-uniform base + lane*16.
__device__ __forceinline__ void gl_lds16(const unsigned short* g, unsigned short* l) {
  __builtin_amdgcn_global_load_lds(
      (const __attribute__((address_space(1))) void*)g,
      (__attribute__((address_space(3))) void*)l, 16, 0, 0);
}

// One launch: x (blocks 0..4095) + 4 weights (blocks 4096..8191, contiguous dst).
__global__ __launch_bounds__(256) void cvt_all_kernel(
    const float* __restrict__ x,
    const float* __restrict__ w0, const float* __restrict__ w1,
    const float* __restrict__ w2, const float* __restrict__ w3,
    unsigned short* __restrict__ xb, unsigned short* __restrict__ wb) {
  const int bid = blockIdx.x;
  const float* src;
  unsigned short* dst;
  int idx;
  if (bid < 4096) {
    src = x; dst = xb;
    idx = bid * 256 + threadIdx.x;
  } else {
    int j = (bid - 4096) * 256 + threadIdx.x;  // float4 index across 4 weights
    int z = j >> 18;                           // 262144 float4 per weight
    src = (z == 0) ? w0 : (z == 1) ? w1 : (z == 2) ? w2 : w3;
    dst = wb + (size_t)z * 1048576;            // 1M shorts per weight
    idx = j & 262143;
  }
  float4v f = ((const float4v*)src)[idx];
  ushort4v o;
#pragma unroll
  for (int q = 0; q < 4; q++) o[q] = f2bf(f[q]);
  ((ushort4v*)dst)[idx] = o;
}

// C = A(bf16 MxK) @ W^T. MT x 128 tile, BK=64, global_load_lds staging.
// LDS layout XOR-swizzled on 16B granules (phys_g = g ^ (row&7)).
// QKV epilogue: z==0 (Q) scales by QSCALE; z==2 (V) stores TRANSPOSED +
// sigma-permuted layout [bh][hd][sig(s)] so attention can stage V via
// global_load_lds with zero pack work. Each lane holds 4 consecutive tokens
// (quad*4+r) at fixed feature o; sigma keeps 4-aligned groups contiguous, so
// the store is one packed b64 at column sig(s0).
template <bool OUTPROJ, int MT>
__global__ __launch_bounds__(256) void gemm_bt_kernel(
    const unsigned short* __restrict__ A,
    const unsigned short* __restrict__ W0,
    const unsigned short* __restrict__ W1,
    const unsigned short* __restrict__ W2,
    unsigned short* __restrict__ q_dst,
    unsigned short* __restrict__ k_dst,
    unsigned short* __restrict__ v_dst,
    float* __restrict__ f_dst,
    const float* __restrict__ bias) {
  constexpr int K = 1024;
  constexpr int NMB = MT / 32;    // 16-row m-blocks per wave
  constexpr int APASS = MT / 32;  // staging passes for A (32 rows each)
  const int z = blockIdx.z;
  const unsigned short* W = (z == 0) ? W0 : (z == 1) ? W1 : W2;
  unsigned short* qkv = (z == 0) ? q_dst : (z == 1) ? k_dst : v_dst;

  __shared__ unsigned short Asm[MT * 64];
  __shared__ unsigned short Bsm[128 * 64];

  const int t = threadIdx.x;
  const int wave = t >> 6, lane = t & 63;
  const int quad = lane >> 4, l16 = lane & 15;
  const int wy = wave >> 1, wx = wave & 1;
  const int row0 = blockIdx.x * MT;
  const int col0 = blockIdx.y * 128;

  float4v zero = {0.f, 0.f, 0.f, 0.f};
  float4v acc[NMB][4];
#pragma unroll
  for (int i = 0; i < NMB; i++)
#pragma unroll
    for (int j = 0; j < 4; j++) acc[i][j] = zero;

  // staging geometry: pass i covers rows i*32..i*32+31; thread t -> row i*32+(t>>3),
  // phys granule t&7, logical granule (t&7)^((t>>3)&7). LDS slot = i*2048 + t*8.
  const int srow = t >> 3;
  const int sgl = ((t & 7) ^ (srow & 7)) << 3;  // logical col in shorts
  const unsigned short* gA[APASS];
  const unsigned short* gB[4];
#pragma unroll
  for (int i = 0; i < APASS; i++)
    gA[i] = A + (size_t)(row0 + i * 32 + srow) * K + sgl;
#pragma unroll
  for (int i = 0; i < 4; i++)
    gB[i] = W + (size_t)(col0 + i * 32 + srow) * K + sgl;

  const int swl = (l16 & 7);  // frag-read swizzle key

  for (int k0 = 0; k0 < K; k0 += 64) {
#pragma unroll
    for (int i = 0; i < APASS; i++) gl_lds16(gA[i] + k0, &Asm[i * 2048 + t * 8]);
#pragma unroll
    for (int i = 0; i < 4; i++) gl_lds16(gB[i] + k0, &Bsm[i * 2048 + t * 8]);
    __syncthreads();
    short8 af[NMB][2], bf[4][2];
#pragma unroll
    for (int ks = 0; ks < 2; ks++) {
#pragma unroll
      for (int mb = 0; mb < NMB; mb++) {
        int row = wy * (MT / 2) + mb * 16 + l16;
        int pg = (ks * 4 + quad) ^ swl;
        af[mb][ks] = *(const short8*)(&Asm[row * 64 + pg * 8]);
      }
#pragma unroll
      for (int nb = 0; nb < 4; nb++) {
        int row = wx * 64 + nb * 16 + l16;
        int pg = (ks * 4 + quad) ^ swl;
        bf[nb][ks] = *(const short8*)(&Bsm[row * 64 + pg * 8]);
      }
    }
#pragma unroll
    for (int ks = 0; ks < 2; ks++)
#pragma unroll
      for (int mb = 0; mb < NMB; mb++)
#pragma unroll
        for (int nb = 0; nb < 4; nb++)
          acc[mb][nb] = __builtin_amdgcn_mfma_f32_16x16x32_bf16(af[mb][ks], bf[nb][ks], acc[mb][nb], 0, 0, 0);
    __syncthreads();
  }

  const float qsc = (!OUTPROJ && z == 0) ? QSCALE : 1.0f;
#pragma unroll
  for (int mb = 0; mb < NMB; mb++) {
#pragma unroll
    for (int nb = 0; nb < 4; nb++) {
      if (OUTPROJ) {
#pragma unroll
        for (int r = 0; r < 4; r++) {
          int row = row0 + wy * (MT / 2) + mb * 16 + quad * 4 + r;
          int o = col0 + wx * 64 + nb * 16 + l16;
          f_dst[(size_t)row * 1024 + o] = acc[mb][nb][r] + bias[o];
        }
      } else if (z == 2) {
        // V^T + sigma: rowb = 4-aligned token base (b constant across r).
        int rowb = row0 + wy * (MT / 2) + mb * 16 + quad * 4;
        int b = rowb >> 11, s0 = rowb & 2047;
        int o = col0 + wx * 64 + nb * 16 + l16;
        int h = o >> 6, hd = o & 63;
        int c = (s0 & ~31) + (((s0 >> 2) & 3) << 3) + (((s0 >> 4) & 1) << 2);
        ushort4v p4;
#pragma unroll
        for (int r = 0; r < 4; r++) p4[r] = f2bf(acc[mb][nb][r]);
        *(ushort4v*)(qkv + ((size_t)((b * Hq + h) * HDq + hd)) * Sq + c) = p4;
      } else {
#pragma unroll
        for (int r = 0; r < 4; r++) {
          int row = row0 + wy * (MT / 2) + mb * 16 + quad * 4 + r;
          int o = col0 + wx * 64 + nb * 16 + l16;
          int b = row >> 11, s = row & 2047;
          int h = o >> 6, hd = o & 63;
          qkv[(size_t)((b * Hq + h) * Sq + s) * HDq + hd] = f2bf(acc[mb][nb][r] * qsc);
        }
      }
    }
  }
}

// Flash attention v9 (session-best structure, 47.5-48.6us measured): V pack
// eliminated — V arrives pre-transposed + pre-sigma'd from the QKV GEMM
// ([bh][hd][sig(s)]), so V staging is a clone of the verified K path:
// global_load_lds, XOR-swizzled granules, zero VALU, zero ds_writes.
// SQ_LDS_BANK_CONFLICT 65K (vs 2.16M with in-kernel pack).
// v12 delta: s_setprio(1) around the MFMA clusters (clean A/B — v7 tested
// setprio only confounded with its runtime-P regression). Compile-time P
// indices intact.
// 512 threads, 8 waves = 4 q-groups x 2 key-groups, 128-key tiles,
// double-buffered K+V, one barrier per tile, wk-partial combine epilogue,
// XCD-swizzled flat grid (FETCH 4x drop).
// Negative results this session (do not revisit): K-from-global (v6, +43us),
// V-from-global frags (v10, +26us), 64q/wave (v3/v11, occupancy cliff),
// substep stagger (v7), 4-block desync (v8), MT=128 outproj (r10, 1 blk/CU).
__global__ __launch_bounds__(512, 4) void attn_kernel(
    const unsigned short* __restrict__ Q,
    const unsigned short* __restrict__ Kg,
    const unsigned short* __restrict__ Vt,
    unsigned short* __restrict__ ctx) {
  constexpr int KBUF = 8192;  // shorts per K buffer (128 keys x 64 hd, swizzled)
  constexpr int VBUF = 8192;  // shorts per V^T buffer (64 hd x 128 keys, swizzled)
  constexpr int QSTR = 132;   // obuf q-dim stride (f32)
  __shared__ __align__(16) unsigned char smem[65536];
  unsigned short* Ksm = (unsigned short*)smem;            // [2][8192]
  unsigned short* Vsm = (unsigned short*)(smem + 32768);  // [2][8192]
  float* obuf = (float*)smem;                             // combine: [64 hd][132 q]
  float* dbuf = (float*)(smem + 33792);                   // combine: [128]

  const int wgid = blockIdx.x;
  const int lid = wgid >> 3;
  const int bh = (wgid & 7) * 4 + (lid >> 4);  // XCD-co-located bh
  const int q0 = (lid & 15) * 128;
  const int t = threadIdx.x;
  const int wave = t >> 6, lane = t & 63;
  const int quad = lane >> 4, l16 = lane & 15;
  const int wq = wave >> 1, wk = wave & 1;
  const int swl = l16 & 7;

  const unsigned short* Qb = Q + (size_t)bh * Sq * HDq;
  const unsigned short* Kb = Kg + (size_t)bh * Sq * HDq;
  const unsigned short* Vb = Vt + (size_t)bh * HDq * Sq;  // V^T base

  // Q fragments: wave's 32 q rows (B-operand of QK^T S^T-trick MFMA)
  short8 qf[2][2];
#pragma unroll
  for (int qb = 0; qb < 2; qb++)
#pragma unroll
    for (int ks = 0; ks < 2; ks++)
      qf[qb][ks] = *(const short8*)(Qb + (size_t)(q0 + wq * 32 + qb * 16 + l16) * HDq + ks * 32 + quad * 8);

  short8 ones;
#pragma unroll
  for (int j = 0; j < 8; j++) ones[j] = (short)0x3F80;  // bf16 1.0

  float4v zero = {0.f, 0.f, 0.f, 0.f};
  float4v of[2][4];   // [qb][hb]; D layout row=q (quad*4+r), col=hd (l16)
  float4v dsum[2];
#pragma unroll
  for (int qb = 0; qb < 2; qb++) {
    dsum[qb] = zero;
#pragma unroll
    for (int hb = 0; hb < 4; hb++) of[qb][hb] = zero;
  }

  // K staging: 2 passes x 512 threads x 16B; pass i row = i*64 + (t>>3);
  // XOR swizzle on 8 granules pre-applied to the global address.
  const int srow = t >> 3;
  const unsigned short* gK = Kb + (size_t)srow * 64 + (((t & 7) ^ (srow & 7)) << 3);

  // V^T staging: 2 passes; pass i covers hd rows i*32 + (t>>4); 16 granules
  // per 256B row, logical granule (t&15)^(row&15) pre-applied (row&15 is
  // pass-invariant).
  const int vrow = t >> 4;
  const unsigned short* gV = Vb + (size_t)vrow * Sq + (((t & 15) ^ (vrow & 15)) << 3);

#define KISSUE(off, bufsel) do {                                     \
    gl_lds16(gK + (size_t)(off) * 64, &Ksm[(bufsel) * KBUF + t * 8]);\
    gl_lds16(gK + (size_t)(off) * 64 + 4096,                         \
             &Ksm[(bufsel) * KBUF + 4096 + t * 8]);                  \
  } while (0)

#define VISSUE(off, bufsel) do {                                     \
    gl_lds16(gV + (off), &Vsm[(bufsel) * VBUF + t * 8]);             \
    gl_lds16(gV + (off) + 32 * Sq,                                   \
             &Vsm[(bufsel) * VBUF + 4096 + t * 8]);                  \
  } while (0)

  // one 32-key substep: QK/exp2/pack/dsum; vf reads the swizzled V^T tile
  // (sigma key order matches pfr pack order). setprio(1) around MFMA
  // clusters (T5; zero correctness impact).
#define PSTEP(P, BUF) do {                                                     \
    const int kb0 = (BUF) * KBUF + wk * 4096 + (P) * 2048;                     \
    short8 kf[2][2];                                                           \
    _Pragma("unroll")                                                          \
    for (int s = 0; s < 2; s++)                                                \
      _Pragma("unroll")                                                        \
      for (int ks = 0; ks < 2; ks++)                                           \
        kf[s][ks] = *(const short8*)&Ksm[kb0 + (s * 16 + l16) * 64 + ((ks * 4 + quad) ^ swl) * 8]; \
    short8 pfr[2];                                                             \
    _Pragma("unroll")                                                          \
    for (int qb = 0; qb < 2; qb++) {                                           \
      float4v sa = zero, sb = zero;                                            \
      __builtin_amdgcn_s_setprio(1);                                           \
      _Pragma("unroll")                                                        \
      for (int ks = 0; ks < 2; ks++) {                                         \
        sa = __builtin_amdgcn_mfma_f32_16x16x32_bf16(kf[0][ks], qf[qb][ks], sa, 0, 0, 0); \
        sb = __builtin_amdgcn_mfma_f32_16x16x32_bf16(kf[1][ks], qf[qb][ks], sb, 0, 0, 0); \
      }                                                                        \
      __builtin_amdgcn_s_setprio(0);                                           \
      union { uint32_t u[4]; short8 v; } pw;                                   \
      pw.u[0] = pk2bf(__builtin_amdgcn_exp2f(sa[0]), __builtin_amdgcn_exp2f(sa[1])); \
      pw.u[1] = pk2bf(__builtin_amdgcn_exp2f(sa[2]), __builtin_amdgcn_exp2f(sa[3])); \
      pw.u[2] = pk2bf(__builtin_amdgcn_exp2f(sb[0]), __builtin_amdgcn_exp2f(sb[1])); \
      pw.u[3] = pk2bf(__builtin_amdgcn_exp2f(sb[2]), __builtin_amdgcn_exp2f(sb[3])); \
      pfr[qb] = pw.v;                                                          \
    }                                                                          \
    __builtin_amdgcn_s_setprio(1);                                             \
    _Pragma("unroll")                                                          \
    for (int qb = 0; qb < 2; qb++)                                             \
      dsum[qb] = __builtin_amdgcn_mfma_f32_16x16x32_bf16(pfr[qb], ones, dsum[qb], 0, 0, 0); \
    _Pragma("unroll")                                                          \
    for (int hb = 0; hb < 4; hb++) {                                           \
      short8 vf = *(const short8*)&Vsm[(BUF) * VBUF + (hb * 16 + l16) * 128 + ((wk * 8 + (P) * 4 + quad) ^ l16) * 8]; \
      _Pragma("unroll")                                                        \
      for (int qb = 0; qb < 2; qb++)                                           \
        of[qb][hb] = __builtin_amdgcn_mfma_f32_16x16x32_bf16(pfr[qb], vf, of[qb][hb], 0, 0, 0); \
    }                                                                          \
    __builtin_amdgcn_s_setprio(0);                                             \
  } while (0)

  // prologue: tile 0 into buf0; barrier drains; tile 1 into buf1 (in flight
  // during tile-0 compute, drained by the in-loop barrier).
  KISSUE(0, 0);
  VISSUE(0, 0);
  __syncthreads();
  KISSUE(128, 1);
  VISSUE(128, 1);

  for (int kt = 0; kt < Sq; kt += 128) {
    const int cur = (kt >> 7) & 1;
    PSTEP(0, cur);
    PSTEP(1, cur);
    __syncthreads();
    if (kt + 256 < Sq) {
      KISSUE(kt + 256, cur);
      VISSUE(kt + 256, cur);
    }
  }

  // combine the 2 key-group partials in LDS: obuf[hd][q] f32, float4 stores
  // along q (quad*4+r contiguous). Overlays K/V buffers (safe after barrier).
  if (wk == 0) {
#pragma unroll
    for (int qb = 0; qb < 2; qb++) {
#pragma unroll
      for (int hb = 0; hb < 4; hb++)
        *(float4v*)&obuf[(hb * 16 + l16) * QSTR + wq * 32 + qb * 16 + quad * 4] = of[qb][hb];
      if (l16 == 0)
#pragma unroll
        for (int r = 0; r < 4; r++)
          dbuf[wq * 32 + qb * 16 + quad * 4 + r] = dsum[qb][r];
    }
  }
  __syncthreads();
  if (wk == 1) {
#pragma unroll
    for (int qb = 0; qb < 2; qb++) {
#pragma unroll
      for (int hb = 0; hb < 4; hb++) {
        float4v* pp = (float4v*)&obuf[(hb * 16 + l16) * QSTR + wq * 32 + qb * 16 + quad * 4];
        float4v o = *pp;
        o += of[qb][hb];
        *pp = o;
      }
      if (l16 == 0)
#pragma unroll
        for (int r = 0; r < 4; r++)
          dbuf[wq * 32 + qb * 16 + quad * 4 + r] += dsum[qb][r];
    }
  }
  __syncthreads();

  // final store: thread t -> q row (t&127), 16-hd segment (t>>7)
  const int b = bh >> 4, h = bh & 15;
  const int qq = t & 127, hseg = t >> 7;
  const float dinv = 1.0f / dbuf[qq];
  unsigned short* cp = ctx + ((size_t)(b * Sq + q0 + qq)) * Dq + h * 64 + hseg * 16;
  short8 o8a, o8b;
#pragma unroll
  for (int j = 0; j < 8; j++) o8a[j] = (short)f2bf(obuf[(hseg * 16 + j) * QSTR + qq] * dinv);
#pragma unroll
  for (int j = 0; j < 8; j++) o8b[j] = (short)f2bf(obuf[(hseg * 16 + 8 + j) * QSTR + qq] * dinv);
  *(short8*)cp = o8a;
  *(short8*)(cp + 8) = o8b;
#undef KISSUE
#undef VISSUE
#undef PSTEP
}

extern "C" void kernel_launch(void* const* d_in, const int* in_sizes, int n_in,
                              void* d_out, int out_size, void* d_ws, size_t ws_size,
                              hipStream_t stream) {
  (void)in_sizes; (void)n_in; (void)out_size; (void)ws_size;
  const float* x  = (const float*)d_in[0];
  const float* wq = (const float*)d_in[1];
  const float* wk = (const float*)d_in[2];
  const float* wv = (const float*)d_in[3];
  const float* wo = (const float*)d_in[4];
  const float* bo = (const float*)d_in[5];
  float* out = (float*)d_out;

  char* ws = (char*)d_ws;
  const size_t MB = 1u << 20;
  unsigned short* xb  = (unsigned short*)(ws + 0 * MB);   // 8 MB  (4096x1024 bf16)
  unsigned short* wqb = (unsigned short*)(ws + 8 * MB);   // 2 MB each, contiguous
  unsigned short* wkb = (unsigned short*)(ws + 10 * MB);
  unsigned short* wvb = (unsigned short*)(ws + 12 * MB);
  unsigned short* wob = (unsigned short*)(ws + 14 * MB);
  unsigned short* qb  = (unsigned short*)(ws + 16 * MB);  // 8 MB  (B,H,S,HD), pre-scaled
  unsigned short* kb  = (unsigned short*)(ws + 24 * MB);  // 8 MB
  unsigned short* vb  = (unsigned short*)(ws + 32 * MB);  // 8 MB  (B,H,HD,sig(S)) V^T
  unsigned short* cxb = (unsigned short*)(ws + 40 * MB);  // 8 MB  (B,S,D)

  cvt_all_kernel<<<8192, 256, 0, stream>>>(x, wq, wk, wv, wo, xb, wqb);

  gemm_bt_kernel<false, 128><<<dim3(32, 8, 3), 256, 0, stream>>>(
      xb, wqb, wkb, wvb, qb, kb, vb, nullptr, nullptr);
  attn_kernel<<<dim3(512), 512, 0, stream>>>(qb, kb, vb, cxb);
  // outproj: MT=64 (512 blocks = 2 blocks/CU) — round-8 verified best.
  gemm_bt_kernel<true, 64><<<dim3(64, 8, 1), 256, 0, stream>>>(
      cxb, wob, wob, wob, nullptr, nullptr, nullptr, out, bo);
}